// Round 1
// baseline (836.855 us; speedup 1.0000x reference)
//
#include <hip/hip_runtime.h>

// PaDiM: B=32 batch, C=192 channels, P=3136 patches.
// out = [P*C means][P*C*C covs], fp32.
// means[i][c] = means_in[i][c] + sum_b emb[b][c][i]
// cov[i][c][d] = cov_in[i][c][d] + sum_b emb[b][c][i]*emb[b][d][i]
constexpr int B = 32;
constexpr int C = 192;
constexpr int P = 3136;

// One block per patch. 256 threads as 16(tx) x 16(ty).
// Thread owns rows c = ty + 16*m (m=0..11), col-float4s d4 = tx + 16*n (n=0..2).
// launch_bounds(256,2): 2 waves/EU -> 2 blocks/CU, VGPR cap 256.
__global__ __launch_bounds__(256, 2) void padim_cov_kernel(
    const float* __restrict__ emb,      // [B][C][P]
    const float* __restrict__ means_in, // [P][C]
    const float* __restrict__ cov_in,   // [P][C][C]
    float* __restrict__ out)            // [P*C + P*C*C]
{
    __shared__ float lds[B * C];  // 24 KB: slice emb[:, :, i]

    // XCD-bijective swizzle (P % 8 == 0): consecutive patches share an XCD's L2
    // so the stride-P staging loads reuse 64B lines across neighboring blocks.
    const int bid = blockIdx.x;
    constexpr int CPX = P / 8;
    const int i = (bid & 7) * CPX + (bid >> 3);

    const int t = threadIdx.x;

    // Stage slice: lds[b*C + c] = emb[b][c][i]. Stride-P gather (small traffic).
    for (int e = t; e < B * C; e += 256) {
        lds[e] = emb[(size_t)e * P + i];
    }
    __syncthreads();

    const int tx = t & 15;
    const int ty = t >> 4;

    float4 acc[12][3];
    #pragma unroll
    for (int m = 0; m < 12; ++m)
        #pragma unroll
        for (int n = 0; n < 3; ++n)
            acc[m][n] = make_float4(0.f, 0.f, 0.f, 0.f);

    #pragma unroll 2
    for (int b = 0; b < B; ++b) {
        const float* row = lds + b * C;
        float av[12];
        float4 bv[3];
        #pragma unroll
        for (int m = 0; m < 12; ++m) av[m] = row[ty + 16 * m];          // broadcast reads
        #pragma unroll
        for (int n = 0; n < 3; ++n)                                     // ds_read_b128, 2-way (free)
            bv[n] = *reinterpret_cast<const float4*>(row + 4 * (tx + 16 * n));
        #pragma unroll
        for (int m = 0; m < 12; ++m) {
            #pragma unroll
            for (int n = 0; n < 3; ++n) {
                acc[m][n].x += av[m] * bv[n].x;
                acc[m][n].y += av[m] * bv[n].y;
                acc[m][n].z += av[m] * bv[n].z;
                acc[m][n].w += av[m] * bv[n].w;
            }
        }
    }

    // Means: one thread per channel.
    if (t < C) {
        float s = 0.f;
        #pragma unroll
        for (int b = 0; b < B; ++b) s += lds[b * C + t];
        out[(size_t)i * C + t] = means_in[(size_t)i * C + t] + s;
    }

    // Cov epilogue: coalesced float4 read-modify-write (16 lanes = 256B contiguous).
    float* covo = out + (size_t)P * C;
    const size_t base = (size_t)i * C * C;
    #pragma unroll
    for (int m = 0; m < 12; ++m) {
        const int c = ty + 16 * m;
        #pragma unroll
        for (int n = 0; n < 3; ++n) {
            const size_t idx = base + (size_t)c * C + 4 * (tx + 16 * n);
            const float4 cv = *reinterpret_cast<const float4*>(cov_in + idx);
            float4 r;
            r.x = cv.x + acc[m][n].x;
            r.y = cv.y + acc[m][n].y;
            r.z = cv.z + acc[m][n].z;
            r.w = cv.w + acc[m][n].w;
            *reinterpret_cast<float4*>(covo + idx) = r;
        }
    }
}

extern "C" void kernel_launch(void* const* d_in, const int* in_sizes, int n_in,
                              void* d_out, int out_size, void* d_ws, size_t ws_size,
                              hipStream_t stream) {
    const float* emb      = (const float*)d_in[0];
    const float* means_in = (const float*)d_in[1];
    const float* cov_in   = (const float*)d_in[2];
    float* out            = (float*)d_out;
    padim_cov_kernel<<<P, 256, 0, stream>>>(emb, means_in, cov_in, out);
}

// Round 2
// 811.158 us; speedup vs baseline: 1.0317x; 1.0317x over previous
//
#include <hip/hip_runtime.h>

// PaDiM: B=32 batch, C=192 channels, P=3136 patches.
// out = [P*C means][P*C*C covs], fp32.
// means[i][c] = means_in[i][c] + sum_b emb[b][c][i]
// cov[i][c][d] = cov_in[i][c][d] + sum_b emb[b][c][i]*emb[b][d][i]
constexpr int B = 32;
constexpr int C = 192;
constexpr int P = 3136;

// One block per patch, 256 threads = 16(tx) x 16(ty).
// Rows (c) processed in TWO groups of 96 so the accumulator tile is
// acc[6][3] float4 = 72 VGPRs (the R1 144-reg tile forced the compiler to
// restructure at VGPR=128, serializing cov_in loads onto the critical path).
// cov_in is prefetched INTO the accumulator (RMW for free, loads issue as one
// independent burst before the FMA loop).
__global__ __launch_bounds__(256, 3) void padim_cov_kernel(
    const float* __restrict__ emb,      // [B][C][P]
    const float* __restrict__ means_in, // [P][C]
    const float* __restrict__ cov_in,   // [P][C][C]
    float* __restrict__ out)            // [P*C + P*C*C]
{
    __shared__ float lds[B * C];  // 24 KB: slice emb[:, :, i]

    // XCD-bijective swizzle (P % 8 == 0): consecutive patches share an XCD's
    // L2 so stride-P staging loads reuse 64B lines across neighboring blocks.
    const int bid = blockIdx.x;
    constexpr int CPX = P / 8;
    const int i = (bid & 7) * CPX + (bid >> 3);

    const int t = threadIdx.x;

    // Stage slice: lds[b*C + c] = emb[b][c][i]. 24 scalar loads/thread.
    for (int e = t; e < B * C; e += 256) {
        lds[e] = emb[(size_t)e * P + i];
    }
    __syncthreads();

    const int tx = t & 15;
    const int ty = t >> 4;

    float* covo = out + (size_t)P * C;
    const size_t base = (size_t)i * (size_t)(C * C);

    #pragma unroll 1   // keep the two groups' register tiles from co-existing
    for (int g = 0; g < 2; ++g) {
        const int rowoff = 96 * g + ty;

        // Prefetch cov_in tile; accumulate directly into it (18 independent
        // ds-independent global b128 loads in flight).
        float4 acc[6][3];
        #pragma unroll
        for (int m = 0; m < 6; ++m) {
            const size_t rbase = base + (size_t)(rowoff + 16 * m) * C;
            #pragma unroll
            for (int n = 0; n < 3; ++n)
                acc[m][n] = *reinterpret_cast<const float4*>(cov_in + rbase + 4 * (tx + 16 * n));
        }

        #pragma unroll 2
        for (int b = 0; b < B; ++b) {
            const float* row = lds + b * C;
            float av[6];
            float4 bv[3];
            #pragma unroll
            for (int m = 0; m < 6; ++m) av[m] = row[rowoff + 16 * m];     // broadcast
            #pragma unroll
            for (int n = 0; n < 3; ++n)                                    // b128, dup-broadcast (free)
                bv[n] = *reinterpret_cast<const float4*>(row + 4 * (tx + 16 * n));
            #pragma unroll
            for (int m = 0; m < 6; ++m)
                #pragma unroll
                for (int n = 0; n < 3; ++n) {
                    acc[m][n].x += av[m] * bv[n].x;
                    acc[m][n].y += av[m] * bv[n].y;
                    acc[m][n].z += av[m] * bv[n].z;
                    acc[m][n].w += av[m] * bv[n].w;
                }
        }

        // Pure stores: 16 lanes x float4 = 256B contiguous per quarter-wave.
        #pragma unroll
        for (int m = 0; m < 6; ++m) {
            const size_t rbase = base + (size_t)(rowoff + 16 * m) * C;
            #pragma unroll
            for (int n = 0; n < 3; ++n)
                *reinterpret_cast<float4*>(covo + rbase + 4 * (tx + 16 * n)) = acc[m][n];
        }
    }

    // Means: one thread per channel.
    if (t < C) {
        float s = 0.f;
        #pragma unroll
        for (int b = 0; b < B; ++b) s += lds[b * C + t];
        out[(size_t)i * C + t] = means_in[(size_t)i * C + t] + s;
    }
}

extern "C" void kernel_launch(void* const* d_in, const int* in_sizes, int n_in,
                              void* d_out, int out_size, void* d_ws, size_t ws_size,
                              hipStream_t stream) {
    const float* emb      = (const float*)d_in[0];
    const float* means_in = (const float*)d_in[1];
    const float* cov_in   = (const float*)d_in[2];
    float* out            = (float*)d_out;
    padim_cov_kernel<<<P, 256, 0, stream>>>(emb, means_in, cov_in, out);
}